// Round 1
// baseline (265.863 us; speedup 1.0000x reference)
//
#include <hip/hip_runtime.h>
#include <math.h>

#define H 4
#define NL 5
#define SEQ 610
#define BATCH 128
#define TICKS (SEQ + NL - 1)   // 614: wavefront-pipelined over layers

// ---- fast activations (native v_exp_f32 / v_rcp_f32, ~1 ulp) ----
__device__ __forceinline__ float sigm(float x) {
    return __builtin_amdgcn_rcpf(1.0f + __expf(-x));
}
__device__ __forceinline__ float ftanh(float x) {
    float ax = __builtin_fabsf(x);
    float t  = __expf(-2.0f * ax);                  // in (0,1], no overflow
    float r  = (1.0f - t) * __builtin_amdgcn_rcpf(1.0f + t);
    return __builtin_copysignf(r, x);
}

// DPP quad_perm broadcast of lane (base&~3)+IDX within each 4-lane quad.
// ctrl = idx | idx<<2 | idx<<4 | idx<<6 : 0x00, 0x55, 0xAA, 0xFF
template<int CTRL>
__device__ __forceinline__ float dpp_bcast(float v) {
    return __int_as_float(__builtin_amdgcn_update_dpp(
        0, __float_as_int(v), CTRL, 0xF, 0xF, true));
}
__device__ __forceinline__ float lane_pull(int byte_addr, float v) {
    return __int_as_float(__builtin_amdgcn_ds_bpermute(byte_addr, __float_as_int(v)));
}

// Lane layout: lane = b_local*20 + l*4 + k  (b_local 0..2, l 0..4, k 0..3)
// Tick tau: group (b,l) computes timestep t = tau - l (gated by validity).
// Comm per tick: own h-quad via 4 DPP bcasts; x-quad for layer l comes from
// group l-1 via 4 ds_bpermute (lane-4). Layer 0 loads x from global (padded
// to 4 inputs with zeros); layer 4 fuses the Linear(4->1) and the [610->5]
// projection into running accumulators.
__global__ __launch_bounds__(64) void lstm_pipe_kernel(
    const float* __restrict__ x,      // [128,610,2]
    const float* __restrict__ w_ih0,  // [16,2]
    const float* __restrict__ w_ih,   // [4,16,4]
    const float* __restrict__ w_hh,   // [5,16,4]
    const float* __restrict__ b_ih,   // [5,16]
    const float* __restrict__ b_hh,   // [5,16]
    const float* __restrict__ w_lin,  // [1,4]
    const float* __restrict__ b_lin,  // [1]
    const float* __restrict__ w_fc,   // [5,610]
    const float* __restrict__ b_fc,   // [5]
    float* __restrict__ out)          // [128,5]
{
    const int lane    = threadIdx.x;
    const int b_local = lane / 20;
    const int r       = lane % 20;
    const int l       = r / 4;
    const int k       = r % 4;
    const int b       = blockIdx.x * 3 + b_local;
    if (lane >= 60 || b >= BATCH) return;

    // ---- per-lane weights: 4 gates (i,f,g,o) for hidden unit k of layer l ----
    float wi[4][4], wh[4][4], bias[4];
    #pragma unroll
    for (int j = 0; j < 4; ++j) {
        const int row = j * H + k;                 // PyTorch gate order i,f,g,o
        if (l == 0) {
            wi[j][0] = w_ih0[row * 2 + 0];
            wi[j][1] = w_ih0[row * 2 + 1];
            wi[j][2] = 0.0f; wi[j][3] = 0.0f;      // x padded to 4 with zeros
        } else {
            const float4 v = *(const float4*)&w_ih[((l - 1) * 16 + row) * 4];
            wi[j][0] = v.x; wi[j][1] = v.y; wi[j][2] = v.z; wi[j][3] = v.w;
        }
        const float4 u = *(const float4*)&w_hh[(l * 16 + row) * 4];
        wh[j][0] = u.x; wh[j][1] = u.y; wh[j][2] = u.z; wh[j][3] = u.w;
        bias[j] = b_ih[l * 16 + row] + b_hh[l * 16 + row];
    }
    float wl0 = 0, wl1 = 0, wl2 = 0, wl3 = 0, bl = 0;
    if (l == 4) {
        wl0 = w_lin[0]; wl1 = w_lin[1]; wl2 = w_lin[2]; wl3 = w_lin[3];
        bl  = b_lin[0];
    }
    const int bperm_addr = (lane - 4) * 4;         // pull from the group one layer below
    const float* xrow = x + (size_t)b * (SEQ * 2);

    // ---- state ----
    float h = 0.f, c = 0.f;
    float hq0 = 0, hq1 = 0, hq2 = 0, hq3 = 0;      // own-layer h quad (t-1)
    float xq0 = 0, xq1 = 0, xq2 = 0, xq3 = 0;      // layer l-1 h quad (t)
    float accA = 0.f, accB = 0.f;                  // out[j=k], out[j=4] (k==0)
    float wfcA = 0.f, wfcB = 0.f;                  // w_fc values for current tick
    if (l == 0) { xq0 = xrow[0]; xq1 = xrow[1]; }  // x at t=0

    for (int tau = 0; tau < TICKS; ++tau) {
        // ---- prefetch for tick tau+1 (hidden under this tick's compute) ----
        float nx0 = 0.f, nx1 = 0.f, nwA = 0.f, nwB = 0.f;
        if (l == 0) {
            int tn = tau + 1; if (tn > SEQ - 1) tn = SEQ - 1;
            const float2 xv = *(const float2*)&xrow[tn * 2];
            nx0 = xv.x; nx1 = xv.y;
        }
        if (l == 4) {
            int t4n = tau - 3;
            if (t4n < 0) t4n = 0; if (t4n > SEQ - 1) t4n = SEQ - 1;
            nwA = w_fc[k * SEQ + t4n];
            if (k == 0) nwB = w_fc[4 * SEQ + t4n];
        }

        // ---- gates: g[j] = bias + Wi·xq + Wh·hq  (32 FMA, 4 ILP chains) ----
        float g[4];
        #pragma unroll
        for (int j = 0; j < 4; ++j) {
            float a = bias[j];
            a = fmaf(wi[j][0], xq0, a);
            a = fmaf(wi[j][1], xq1, a);
            a = fmaf(wi[j][2], xq2, a);
            a = fmaf(wi[j][3], xq3, a);
            a = fmaf(wh[j][0], hq0, a);
            a = fmaf(wh[j][1], hq1, a);
            a = fmaf(wh[j][2], hq2, a);
            a = fmaf(wh[j][3], hq3, a);
            g[j] = a;
        }
        const float i_ = sigm(g[0]);
        const float f_ = sigm(g[1]);
        const float gg = ftanh(g[2]);
        const float o_ = sigm(g[3]);
        const float cn = fmaf(f_, c, i_ * gg);
        const float hn = o_ * ftanh(cn);

        const int  t     = tau - l;
        const bool valid = (t >= 0) && (t < SEQ);
        c = valid ? cn : 0.0f;                     // zero state outside window
        h = valid ? hn : 0.0f;

        // ---- own-quad gather (VALU-speed DPP broadcasts) ----
        const float q0 = dpp_bcast<0x00>(h);
        const float q1 = dpp_bcast<0x55>(h);
        const float q2 = dpp_bcast<0xAA>(h);
        const float q3 = dpp_bcast<0xFF>(h);

        // ---- cross-layer pass: read layer l-1's fresh quad ----
        const float p0 = lane_pull(bperm_addr, q0);
        const float p1 = lane_pull(bperm_addr, q1);
        const float p2 = lane_pull(bperm_addr, q2);
        const float p3 = lane_pull(bperm_addr, q3);

        // ---- fused output head on layer-4 lanes ----
        if (l == 4) {
            float tval = fmaf(q0, wl0, fmaf(q1, wl1, fmaf(q2, wl2, fmaf(q3, wl3, bl))));
            tval = valid ? tval : 0.0f;
            accA = fmaf(tval, wfcA, accA);
            if (k == 0) accB = fmaf(tval, wfcB, accB);
        }

        // ---- install next-tick inputs ----
        hq0 = q0; hq1 = q1; hq2 = q2; hq3 = q3;
        if (l == 0) { xq0 = nx0; xq1 = nx1; /* xq2,xq3 stay 0 */ }
        else        { xq0 = p0;  xq1 = p1;  xq2 = p2;  xq3 = p3; }
        wfcA = nwA; wfcB = nwB;
    }

    if (l == 4) {
        out[b * 5 + k] = accA + b_fc[k];
        if (k == 0) out[b * 5 + 4] = accB + b_fc[4];
    }
}

extern "C" void kernel_launch(void* const* d_in, const int* in_sizes, int n_in,
                              void* d_out, int out_size, void* d_ws, size_t ws_size,
                              hipStream_t stream)
{
    const float* x     = (const float*)d_in[0];
    const float* w_ih0 = (const float*)d_in[1];
    const float* w_ih  = (const float*)d_in[2];
    const float* w_hh  = (const float*)d_in[3];
    const float* b_ih  = (const float*)d_in[4];
    const float* b_hh  = (const float*)d_in[5];
    const float* w_lin = (const float*)d_in[6];
    const float* b_lin = (const float*)d_in[7];
    const float* w_fc  = (const float*)d_in[8];
    const float* b_fc  = (const float*)d_in[9];
    float* out = (float*)d_out;

    const int blocks = (BATCH + 2) / 3;            // 3 batch elements per wave64
    lstm_pipe_kernel<<<dim3(blocks), dim3(64), 0, stream>>>(
        x, w_ih0, w_ih, w_hh, b_ih, b_hh, w_lin, b_lin, w_fc, b_fc, out);
}

// Round 2
// 187.608 us; speedup vs baseline: 1.4171x; 1.4171x over previous
//
#include <hip/hip_runtime.h>
#include <math.h>

#define H 4
#define NL 5
#define SEQ 610
#define BATCH 128
#define TICKS (SEQ + NL - 1)   // 614 wavefront-pipelined ticks

// update_dpp on float. CTRL: quad_perm 0x00-0xFF, row_shr:N 0x110|N,
// row_bcast15 0x142. BC=bound_ctrl (true -> 0 on invalid src, false -> keep old).
template<int CTRL, bool BC>
__device__ __forceinline__ float dpp(float old_, float src) {
    return __int_as_float(__builtin_amdgcn_update_dpp(
        __float_as_int(old_), __float_as_int(src), CTRL, 0xF, 0xF, BC));
}

// Lane layout (per 32-lane half = one batch element):
//   r = lane&31; layers 0-3 = quads 0-3 of the 16-lane DPP row (r=0..15),
//   layer 4 = quad 0 of the next row (r=16..19); r=20..31 idle (compute junk).
// Cross-layer handoff per tick, all VALU DPP:
//   quad_perm all-gather of h -> q0..q3 (every lane holds its quad)
//   p_i = row_bcast15(q_i)  merged-with  row_shr:4(q_i)   (bound_ctrl=0 keeps
//         the bcast15 value on row-positions 0-3 = the layer-4 lanes)
// Gate weights pre-scaled by -log2(e) (i,f,o) and +2*log2(e) (g) so
// activations are exp2-direct; divisions merged to 2 rcp per tick.
__global__ __launch_bounds__(64) void lstm_dpp_kernel(
    const float* __restrict__ x,      // [128,610,2]
    const float* __restrict__ w_ih0,  // [16,2]
    const float* __restrict__ w_ih,   // [4,16,4]
    const float* __restrict__ w_hh,   // [5,16,4]
    const float* __restrict__ b_ih,   // [5,16]
    const float* __restrict__ b_hh,   // [5,16]
    const float* __restrict__ w_lin,  // [1,4]
    const float* __restrict__ b_lin,  // [1]
    const float* __restrict__ w_fc,   // [5,610]
    const float* __restrict__ b_fc,   // [5]
    float* __restrict__ out)          // [128,5]
{
    __shared__ float lds_x[2 * SEQ * 2];   // [2][610][2]
    __shared__ float lds_wfc[5 * SEQ];     // [5][610]

    const int lane = threadIdx.x;
    const int half = lane >> 5;
    const int r    = lane & 31;
    const int l    = r >> 2;
    const int k    = r & 3;
    const int lw   = l > 4 ? 4 : l;        // clamp idle quads to valid weights
    const bool is_l0 = (l == 0);
    const int  b   = blockIdx.x * 2 + half;

    // ---- stage x (both batches) and w_fc into LDS, coalesced ----
    #pragma unroll
    for (int hh = 0; hh < 2; ++hh) {
        const float4* src = (const float4*)(x + (size_t)(blockIdx.x * 2 + hh) * (SEQ * 2));
        float4* dst = (float4*)&lds_x[hh * (SEQ * 2)];
        for (int i = lane; i < (SEQ * 2) / 4; i += 64) dst[i] = src[i];
    }
    {
        const float2* src = (const float2*)w_fc;
        float2* dst = (float2*)lds_wfc;
        for (int i = lane; i < (5 * SEQ) / 2; i += 64) dst[i] = src[i];
    }
    __syncthreads();

    // ---- per-lane weights (gate j of hidden unit k, layer lw), pre-scaled ----
    float wi[4][4], wh[4][4], bias[4];
    #pragma unroll
    for (int j = 0; j < 4; ++j) {
        const float s = (j == 2) ? 2.8853900817779268f   // +2*log2(e) for g
                                 : -1.4426950408889634f; // -log2(e) for i,f,o
        const int row = j * H + k;
        if (lw == 0) {
            wi[j][0] = w_ih0[row * 2 + 0] * s;
            wi[j][1] = w_ih0[row * 2 + 1] * s;
            wi[j][2] = 0.f; wi[j][3] = 0.f;
        } else {
            const float4 v = *(const float4*)&w_ih[((lw - 1) * 16 + row) * 4];
            wi[j][0] = v.x * s; wi[j][1] = v.y * s; wi[j][2] = v.z * s; wi[j][3] = v.w * s;
        }
        const float4 u = *(const float4*)&w_hh[(lw * 16 + row) * 4];
        wh[j][0] = u.x * s; wh[j][1] = u.y * s; wh[j][2] = u.z * s; wh[j][3] = u.w * s;
        bias[j] = (b_ih[lw * 16 + row] + b_hh[lw * 16 + row]) * s;
    }
    const float wl0 = w_lin[0], wl1 = w_lin[1], wl2 = w_lin[2], wl3 = w_lin[3];
    const float bl  = b_lin[0];

    const int xbase = half * (SEQ * 2);
    const int wfcA_base = k * SEQ;

    // ---- state ----
    float c = 0.f;
    float hq0 = 0.f, hq1 = 0.f, hq2 = 0.f, hq3 = 0.f;
    const float2 xv0 = *(const float2*)&lds_x[xbase];
    float xq0 = is_l0 ? xv0.x : 0.f;
    float xq1 = is_l0 ? xv0.y : 0.f;
    float xq2 = 0.f, xq3 = 0.f;
    float wfcA = 0.f, wfcB = 0.f;
    float accA = 0.f, accB = 0.f;

    #pragma unroll 2
    for (int tau = 0; tau < TICKS; ++tau) {
        // ---- LDS prefetch for tick tau+1 (hidden under this tick's VALU) ----
        int tn = tau + 1; tn = tn > SEQ - 1 ? SEQ - 1 : tn;
        const float2 nx = *(const float2*)&lds_x[xbase + tn * 2];
        int t4 = tau - 3; t4 = t4 < 0 ? 0 : (t4 > SEQ - 1 ? SEQ - 1 : t4);
        const float nwA = lds_wfc[wfcA_base + t4];
        const float nwB = lds_wfc[4 * SEQ + t4];

        // ---- gates (4 independent 8-deep FMA chains, issue-optimal) ----
        float g[4];
        #pragma unroll
        for (int j = 0; j < 4; ++j) {
            float a = bias[j];
            a = fmaf(wi[j][0], xq0, a);
            a = fmaf(wi[j][1], xq1, a);
            a = fmaf(wi[j][2], xq2, a);
            a = fmaf(wi[j][3], xq3, a);
            a = fmaf(wh[j][0], hq0, a);
            a = fmaf(wh[j][1], hq1, a);
            a = fmaf(wh[j][2], hq2, a);
            a = fmaf(wh[j][3], hq3, a);
            g[j] = a;
        }
        // sigmoid(z) = rcp(1+exp2(-z*log2e)); tanh(z) = (D-2)/D, D = exp2(2z*log2e)+1
        const float Ai = 1.f + __builtin_amdgcn_exp2f(g[0]);
        const float Af = 1.f + __builtin_amdgcn_exp2f(g[1]);
        const float Dg = 1.f + __builtin_amdgcn_exp2f(g[2]);
        const float Ao = 1.f + __builtin_amdgcn_exp2f(g[3]);
        // c' = f*c + i*tanh(g) = [c*Ai*Dg + Af*(Dg-2)] / (Af*Ai*Dg)  (one rcp)
        const float M   = Ai * Dg;
        const float den = M * Af;
        const float num = fmaf(c, M, Af * (Dg - 2.f));
        const float cn  = num * __builtin_amdgcn_rcpf(den);
        const unsigned tt = (unsigned)(tau - l);
        c = (tt < SEQ) ? cn : 0.f;          // out-of-window: zero state
        // h = o*tanh(c) = (Dc-2)/(Ao*Dc); c==0 -> h==0 (gating is free)
        const float Dc = 1.f + __builtin_amdgcn_exp2f(c * 2.8853900817779268f);
        const float h  = (Dc - 2.f) * __builtin_amdgcn_rcpf(Ao * Dc);

        // ---- quad all-gather of h (VALU DPP) ----
        const float q0 = dpp<0x00, true>(0.f, h);
        const float q1 = dpp<0x55, true>(0.f, h);
        const float q2 = dpp<0xAA, true>(0.f, h);
        const float q3 = dpp<0xFF, true>(0.f, h);

        // ---- cross-layer handoff: bcast15 (layer4) merged with row_shr:4 ----
        float p0 = dpp<0x142, true>(0.f, q0); p0 = dpp<0x114, false>(p0, q0);
        float p1 = dpp<0x142, true>(0.f, q1); p1 = dpp<0x114, false>(p1, q1);
        float p2 = dpp<0x142, true>(0.f, q2); p2 = dpp<0x114, false>(p2, q2);
        float p3 = dpp<0x142, true>(0.f, q3); p3 = dpp<0x114, false>(p3, q3);

        // ---- fused output head (meaningful on layer-4 lanes; junk elsewhere) ----
        float tval = fmaf(q3, wl3, bl);
        tval = fmaf(q2, wl2, tval);
        tval = fmaf(q1, wl1, tval);
        tval = fmaf(q0, wl0, tval);
        tval = (tt < SEQ) ? tval : 0.f;
        accA = fmaf(tval, wfcA, accA);
        accB = fmaf(tval, wfcB, accB);

        // ---- install next-tick inputs (branchless) ----
        hq0 = q0; hq1 = q1; hq2 = q2; hq3 = q3;
        xq0 = is_l0 ? nx.x : p0;
        xq1 = is_l0 ? nx.y : p1;
        xq2 = is_l0 ? 0.f  : p2;
        xq3 = is_l0 ? 0.f  : p3;
        wfcA = nwA; wfcB = nwB;
    }

    if (r >= 16 && r < 20) {                // layer-4 lanes
        out[b * 5 + k] = accA + b_fc[k];
        if (k == 0) out[b * 5 + 4] = accB + b_fc[4];
    }
}

extern "C" void kernel_launch(void* const* d_in, const int* in_sizes, int n_in,
                              void* d_out, int out_size, void* d_ws, size_t ws_size,
                              hipStream_t stream)
{
    const float* x     = (const float*)d_in[0];
    const float* w_ih0 = (const float*)d_in[1];
    const float* w_ih  = (const float*)d_in[2];
    const float* w_hh  = (const float*)d_in[3];
    const float* b_ih  = (const float*)d_in[4];
    const float* b_hh  = (const float*)d_in[5];
    const float* w_lin = (const float*)d_in[6];
    const float* b_lin = (const float*)d_in[7];
    const float* w_fc  = (const float*)d_in[8];
    const float* b_fc  = (const float*)d_in[9];
    float* out = (float*)d_out;

    lstm_dpp_kernel<<<dim3(BATCH / 2), dim3(64), 0, stream>>>(
        x, w_ih0, w_ih, w_hh, b_ih, b_hh, w_lin, b_lin, w_fc, b_fc, out);
}

// Round 6
// 170.220 us; speedup vs baseline: 1.5619x; 1.1022x over previous
//
#include <hip/hip_runtime.h>
#include <math.h>

#define H 4
#define NL 5
#define SEQ 610
#define BATCH 128
#define TICKS (SEQ + NL - 1)   // 614 wavefront-pipelined ticks

// update_dpp on float. CTRL: quad_perm 0x00/0x55/0xAA/0xFF, row_shr:4 0x114,
// row_bcast15 0x142. BC: true -> 0 on invalid src, false -> keep `old`.
template<int CTRL, bool BC>
__device__ __forceinline__ float dpp(float old_, float src) {
    return __int_as_float(__builtin_amdgcn_update_dpp(
        __float_as_int(old_), __float_as_int(src), CTRL, 0xF, 0xF, BC));
}

// Lane layout (per 32-lane half = one batch element):
//   r = lane&31; layers 0-3 = quads 0-3 of the DPP row (r=0..15),
//   layer 4 = quad 0 of the next row (r=16..19); r>=20 compute junk.
//
// Critical cycle per tick (everything else has >= 1 tick of slack):
//   q -> 4-FMA Wh chain -> exp2 -> merge -> rcp -> c -> exp2 -> rcp -> h -> quad DPP -> q
// pre[j] = bias + Wi·x is computed OFF-cycle from the previous tick's p/nx.
__global__ __launch_bounds__(64) void lstm_cyc_kernel(
    const float* __restrict__ x,      // [128,610,2]
    const float* __restrict__ w_ih0,  // [16,2]
    const float* __restrict__ w_ih,   // [4,16,4]
    const float* __restrict__ w_hh,   // [5,16,4]
    const float* __restrict__ b_ih,   // [5,16]
    const float* __restrict__ b_hh,   // [5,16]
    const float* __restrict__ w_lin,  // [1,4]
    const float* __restrict__ b_lin,  // [1]
    const float* __restrict__ w_fc,   // [5,610]
    const float* __restrict__ b_fc,   // [5]
    float* __restrict__ out)          // [128,5]
{
    __shared__ float lds_x[2 * SEQ * 2 + 16];   // [2][610][2] + pad (unclamped tail reads)
    __shared__ float lds_wfc[5 * SEQ + 16];     // [5][610] + pad

    const int lane = threadIdx.x;
    const int half = lane >> 5;
    const int r    = lane & 31;
    const int l    = r >> 2;
    const int k    = r & 3;
    const int lw   = l > 4 ? 4 : l;
    const bool is_l0 = (l == 0);
    const int  b   = blockIdx.x * 2 + half;

    // ---- stage x (both batch rows) and w_fc into LDS, coalesced ----
    #pragma unroll
    for (int hh = 0; hh < 2; ++hh) {
        const float4* src = (const float4*)(x + (size_t)(blockIdx.x * 2 + hh) * (SEQ * 2));
        float4* dst = (float4*)&lds_x[hh * (SEQ * 2)];
        for (int i = lane; i < (SEQ * 2) / 4; i += 64) dst[i] = src[i];
    }
    {
        const float2* src = (const float2*)w_fc;
        float2* dst = (float2*)lds_wfc;
        for (int i = lane; i < (5 * SEQ) / 2; i += 64) dst[i] = src[i];
    }
    __syncthreads();

    // ---- per-lane weights (gate j of unit k, layer lw), pre-scaled by log2e ----
    float wi[4][4], wh[4][4], bias[4];
    #pragma unroll
    for (int j = 0; j < 4; ++j) {
        const float s = (j == 2) ? 2.8853900817779268f   // +2*log2(e) for g
                                 : -1.4426950408889634f; // -log2(e) for i,f,o
        const int row = j * H + k;
        if (lw == 0) {
            wi[j][0] = w_ih0[row * 2 + 0] * s;
            wi[j][1] = w_ih0[row * 2 + 1] * s;
            wi[j][2] = 0.f; wi[j][3] = 0.f;
        } else {
            const float4 v = *(const float4*)&w_ih[((lw - 1) * 16 + row) * 4];
            wi[j][0] = v.x * s; wi[j][1] = v.y * s; wi[j][2] = v.z * s; wi[j][3] = v.w * s;
        }
        const float4 u = *(const float4*)&w_hh[(lw * 16 + row) * 4];
        wh[j][0] = u.x * s; wh[j][1] = u.y * s; wh[j][2] = u.z * s; wh[j][3] = u.w * s;
        bias[j] = (b_ih[lw * 16 + row] + b_hh[lw * 16 + row]) * s;
    }
    const float wl0 = w_lin[0], wl1 = w_lin[1], wl2 = w_lin[2], wl3 = w_lin[3];
    const float bl  = b_lin[0];

    const int xbase = half * (SEQ * 2);
    const int wfcA_base = k * SEQ;

    // ---- state ----
    float c = 0.f;
    float q0 = 0.f, q1 = 0.f, q2 = 0.f, q3 = 0.f;
    float wfcA = 0.f, wfcB = 0.f, accA = 0.f, accB = 0.f;
    float pre0, pre1, pre2, pre3;
    {   // pre for tick 0: x(0) for layer 0, zeros elsewhere
        const float2 xv0 = *(const float2*)&lds_x[xbase];
        const float xq0 = is_l0 ? xv0.x : 0.f;
        const float xq1 = is_l0 ? xv0.y : 0.f;
        pre0 = fmaf(wi[0][1], xq1, fmaf(wi[0][0], xq0, bias[0]));
        pre1 = fmaf(wi[1][1], xq1, fmaf(wi[1][0], xq0, bias[1]));
        pre2 = fmaf(wi[2][1], xq1, fmaf(wi[2][0], xq0, bias[2]));
        pre3 = fmaf(wi[3][1], xq1, fmaf(wi[3][0], xq0, bias[3]));
    }

    // ---- one tick; GATED adds validity selects + index clamps (head only) ----
    #define TICK_BODY(GATED)                                                          \
    {                                                                                 \
        /* off-cycle LDS prefetch for tick tau+1 */                                   \
        int tn = tau + 1;                                                             \
        int t4 = tau - 3;                                                             \
        if (GATED) t4 = t4 < 0 ? 0 : t4;                                              \
        const float2 nx = *(const float2*)&lds_x[xbase + tn * 2];                     \
        const float nwA = lds_wfc[wfcA_base + t4];                                    \
        const float nwB = lds_wfc[4 * SEQ + t4];                                      \
        /* CYCLE: gates = pre + Wh·q (4-deep) */                                      \
        const float g0 = fmaf(wh[0][3], q3, fmaf(wh[0][2], q2, fmaf(wh[0][1], q1, fmaf(wh[0][0], q0, pre0)))); \
        const float g1 = fmaf(wh[1][3], q3, fmaf(wh[1][2], q2, fmaf(wh[1][1], q1, fmaf(wh[1][0], q0, pre1)))); \
        const float g2 = fmaf(wh[2][3], q3, fmaf(wh[2][2], q2, fmaf(wh[2][1], q1, fmaf(wh[2][0], q0, pre2)))); \
        const float g3 = fmaf(wh[3][3], q3, fmaf(wh[3][2], q2, fmaf(wh[3][1], q1, fmaf(wh[3][0], q0, pre3)))); \
        const float Ai = 1.f + __builtin_amdgcn_exp2f(g0);                            \
        const float Af = 1.f + __builtin_amdgcn_exp2f(g1);                            \
        const float Dg = 1.f + __builtin_amdgcn_exp2f(g2);                            \
        const float Ao = 1.f + __builtin_amdgcn_exp2f(g3);                            \
        const float M   = Ai * Dg;                                                    \
        const float den = M * Af;                                                     \
        const float num = fmaf(c, M, Af * (Dg - 2.f));                                \
        float cn = num * __builtin_amdgcn_rcpf(den);                                  \
        unsigned tt = (unsigned)(tau - l);                                            \
        if (GATED) cn = (tt < SEQ) ? cn : 0.f;                                        \
        c = cn;                                                                       \
        const float Dc = 1.f + __builtin_amdgcn_exp2f(c * 2.8853900817779268f);       \
        const float h  = (Dc - 2.f) * __builtin_amdgcn_rcpf(Ao * Dc);                 \
        /* CYCLE: quad all-gather */                                                  \
        const float nq0 = dpp<0x00, true>(0.f, h);                                    \
        const float nq1 = dpp<0x55, true>(0.f, h);                                    \
        const float nq2 = dpp<0xAA, true>(0.f, h);                                    \
        const float nq3 = dpp<0xFF, true>(0.f, h);                                    \
        /* off-cycle: cross-layer handoff (1 tick of slack) */                        \
        float p0 = dpp<0x142, true>(0.f, nq0); p0 = dpp<0x114, false>(p0, nq0);       \
        float p1 = dpp<0x142, true>(0.f, nq1); p1 = dpp<0x114, false>(p1, nq1);       \
        float p2 = dpp<0x142, true>(0.f, nq2); p2 = dpp<0x114, false>(p2, nq2);       \
        float p3 = dpp<0x142, true>(0.f, nq3); p3 = dpp<0x114, false>(p3, nq3);       \
        const float xq0 = is_l0 ? nx.x : p0;                                          \
        const float xq1 = is_l0 ? nx.y : p1;                                          \
        /* off-cycle: pre for next tick (wi[2],wi[3]=0 for layer 0) */                \
        pre0 = fmaf(wi[0][3], p3, fmaf(wi[0][2], p2, fmaf(wi[0][1], xq1, fmaf(wi[0][0], xq0, bias[0])))); \
        pre1 = fmaf(wi[1][3], p3, fmaf(wi[1][2], p2, fmaf(wi[1][1], xq1, fmaf(wi[1][0], xq0, bias[1])))); \
        pre2 = fmaf(wi[2][3], p3, fmaf(wi[2][2], p2, fmaf(wi[2][1], xq1, fmaf(wi[2][0], xq0, bias[2])))); \
        pre3 = fmaf(wi[3][3], p3, fmaf(wi[3][2], p2, fmaf(wi[3][1], xq1, fmaf(wi[3][0], xq0, bias[3])))); \
        /* off-cycle: fused output head (layer-4 lanes) */                            \
        float tval = fmaf(nq3, wl3, bl);                                              \
        tval = fmaf(nq2, wl2, tval);                                                  \
        tval = fmaf(nq1, wl1, tval);                                                  \
        tval = fmaf(nq0, wl0, tval);                                                  \
        if (GATED) tval = (tt < SEQ) ? tval : 0.f;                                    \
        accA = fmaf(tval, wfcA, accA);                                                \
        accB = fmaf(tval, wfcB, accB);                                                \
        q0 = nq0; q1 = nq1; q2 = nq2; q3 = nq3;                                       \
        wfcA = nwA; wfcB = nwB;                                                       \
    }

    // head: gated (layers warm up; out-of-window state forced to 0)
    for (int tau = 0; tau < 4; ++tau) TICK_BODY(true);
    // body + tail: clean. Tail junk in layers 0-3 needs 4 ticks to reach layer 4
    // and the loop ends first; all unclamped LDS reads stay inside the padded arrays.
    #pragma unroll 2
    for (int tau = 4; tau < TICKS; ++tau) TICK_BODY(false);
    #undef TICK_BODY

    if (r >= 16 && r < 20) {                // layer-4 lanes
        out[b * 5 + k] = accA + b_fc[k];
        if (k == 0) out[b * 5 + 4] = accB + b_fc[4];
    }
}

extern "C" void kernel_launch(void* const* d_in, const int* in_sizes, int n_in,
                              void* d_out, int out_size, void* d_ws, size_t ws_size,
                              hipStream_t stream)
{
    const float* x     = (const float*)d_in[0];
    const float* w_ih0 = (const float*)d_in[1];
    const float* w_ih  = (const float*)d_in[2];
    const float* w_hh  = (const float*)d_in[3];
    const float* b_ih  = (const float*)d_in[4];
    const float* b_hh  = (const float*)d_in[5];
    const float* w_lin = (const float*)d_in[6];
    const float* b_lin = (const float*)d_in[7];
    const float* w_fc  = (const float*)d_in[8];
    const float* b_fc  = (const float*)d_in[9];
    float* out = (float*)d_out;

    lstm_cyc_kernel<<<dim3(BATCH / 2), dim3(64), 0, stream>>>(
        x, w_ih0, w_ih, w_hh, b_ih, b_hh, w_lin, b_lin, w_fc, b_fc, out);
}